// Round 1
// baseline (321.567 us; speedup 1.0000x reference)
//
#include <hip/hip_runtime.h>

// Problem constants
#define BB 4
#define CC 32
#define HH 224
#define WW 224
#define LL (HH * WW)            // 50176
#define KK2 25
#define TILE 256
#define TILES_PER_B (LL / TILE) // 196 exact

// out[b,c2,l2] = input[b,c2,l2] * sum_k2 W(b,l2,k2) * V(b, n)
//   n = c2*1254400 + k2*50176 + l2
//   l = n/800, c = (n%800)/25, s = n%25, dy = s/5-2, dx = s%5-2
//   V = input[b, c, y(l)+dy, x(l)+dx]  (0 if OOB)
//   W = pos[k2]*pw + cd[b,l2,k2]*cw
// Decomposition: mm = 576*k2 + l2; q = mm/800; r = mm%800 (c2-independent!)
//   l = c2*1568 + 62*k2 + q;  y = 7*c2 + ys, x = xs with sk = 62*k2+q
//   gather addr = c*LL + yrel*224 + xclamped + c2*1568
//   y-OOB only possible at c2==0 (yrel<0) or c2==31 (yrel>6).

__global__ __launch_bounds__(TILE) void conv_local_kernel(
    const float* __restrict__ input,
    const float* __restrict__ cd,
    const float* __restrict__ colw,
    const float* __restrict__ posw,
    float* __restrict__ out)
{
    __shared__ float cds[TILE * KK2];

    const int blk  = blockIdx.x;
    const int b    = blk / TILES_PER_B;
    const int tile = blk % TILES_PER_B;
    const int l2_0 = tile * TILE;
    const int t    = threadIdx.x;
    const int l2   = l2_0 + t;

    // stage cd tile coalesced: layout identical flat copy
    {
        const float* cd_blk = cd + ((size_t)b * LL + l2_0) * KK2;
        #pragma unroll
        for (int i = 0; i < KK2; ++i)
            cds[i * TILE + t] = cd_blk[i * TILE + t];
    }
    __syncthreads();

    const float cw = colw[0];
    const float pw = posw[0];

    const float* __restrict__ in_b  = input + (size_t)b * CC * LL;
    float* __restrict__       out_b = out   + (size_t)b * CC * LL;

    int   A[KK2];   // gather address for c2-term (add c2*1568)
    float Wt[KK2];  // weight with x-mask folded in

    float acc0 = 0.f, acc31 = 0.f;

    const float POS[KK2] = {8,5,4,5,8, 5,2,1,2,5, 4,1,0,1,4, 5,2,1,2,5, 8,5,4,5,8};

    #pragma unroll
    for (int k2 = 0; k2 < KK2; ++k2) {
        unsigned mm = (unsigned)(576 * k2 + l2);   // < 64000
        unsigned q  = mm / 800u;
        unsigned r  = mm - q * 800u;
        unsigned c  = r / 25u;                     // source channel [0,31]
        unsigned s  = r - c * 25u;                 // window elem [0,24]
        int dy = (int)(s / 5u) - 2;
        int dx = (int)(s % 5u) - 2;
        unsigned sk = 62u * (unsigned)k2 + q;      // <= 1567
        unsigned ys = sk / 224u;                   // [0,6]
        int xs = (int)(sk - ys * 224u);
        int yrel = (int)ys + dy;                   // [-2, 8]
        int xx   = xs + dx;                        // [-2, 225]
        bool xok = ((unsigned)xx) < 224u;
        int xxc  = min(max(xx, 0), 223);
        float w  = fmaf(cds[t * KK2 + k2], cw, POS[k2] * pw);
        float wm = xok ? w : 0.0f;
        Wt[k2] = wm;
        int base = (int)c * LL + xxc;
        A[k2]  = base + yrel * 224;

        // c2 = 0: y = yrel, OOB iff yrel < 0 (clamped addr stays valid)
        {
            int y0  = max(yrel, 0);
            float v = in_b[base + y0 * 224];
            v = (yrel >= 0) ? v : 0.0f;
            acc0 = fmaf(v, wm, acc0);
        }
        // c2 = 31: y = 217 + yrel, OOB iff yrel > 6
        {
            int y31 = 217 + min(yrel, 6);
            float v = in_b[base + y31 * 224];
            v = (yrel <= 6) ? v : 0.0f;
            acc31 = fmaf(v, wm, acc31);
        }
    }

    out_b[l2] = acc0 * in_b[l2];

    // c2 in [1,30]: y = 7*c2 + yrel in [5,218] — always in-bounds
    #pragma unroll 2
    for (int c2 = 1; c2 < CC - 1; ++c2) {
        const int off = c2 * 1568;
        float acc = 0.f;
        #pragma unroll
        for (int k2 = 0; k2 < KK2; ++k2) {
            acc = fmaf(in_b[A[k2] + off], Wt[k2], acc);
        }
        out_b[c2 * LL + l2] = acc * in_b[c2 * LL + l2];
    }

    out_b[31 * LL + l2] = acc31 * in_b[31 * LL + l2];
}

extern "C" void kernel_launch(void* const* d_in, const int* in_sizes, int n_in,
                              void* d_out, int out_size, void* d_ws, size_t ws_size,
                              hipStream_t stream) {
    const float* input = (const float*)d_in[0];
    const float* cdist = (const float*)d_in[1];
    const float* cwp   = (const float*)d_in[2];
    const float* pwp   = (const float*)d_in[3];
    float* o = (float*)d_out;

    dim3 grid(BB * TILES_PER_B);   // 784 blocks
    dim3 block(TILE);              // 256 threads
    hipLaunchKernelGGL(conv_local_kernel, grid, block, 0, stream,
                       input, cdist, cwp, pwp, o);
}

// Round 2
// 181.515 us; speedup vs baseline: 1.7716x; 1.7716x over previous
//
#include <hip/hip_runtime.h>

// Problem constants
#define BB 4
#define CC 32
#define LL 50176              // 224*224
#define KK2 25
#define CDTOT (BB * LL * KK2) // 5,017,600 floats in cd

// out[b,c2,l2] = in[b,c2,l2] * sum_k2 Wt(b,l2,k2) * V(b,n),
//   n = c2*1254400 + k2*50176 + l2 ; decode l=n/800, c=(n%800)/25, s=n%25.
// With m = 576*k2 + l2 and lanes striding l2 by 800 (l2 = rem + 800*ii):
//   r = (576*k2+rem)%800  -> (c,s,dy,dx) wave-uniform (scalar!)
//   q = (576*k2+rem)/800 + ii -> gather address consecutive per lane.
//   addr = c*LL + (7*c2 + ys + dy)*224 + clamp(xs+dx), u = 62*k2+q, ys=u/224, xs=u%224.
// y-OOB only at c2==0 (yy<0) / c2==31 (yy>6) -> masked special iterations.
// c2 split across gridDim.y (chunks of 16) for occupancy.

__global__ __launch_bounds__(256) void conv_local_kernel(
    const float* __restrict__ input,
    const float* __restrict__ cd,
    const float* __restrict__ colw,
    const float* __restrict__ posw,
    float* __restrict__ out)
{
    __shared__ float cds[64 * 101 + 4];   // cd staged: [ii][ (rem-rem0)*25 + k2 ], pad 101
    __shared__ float sx[2][4 * 65];       // S exchange (mapping A -> mapping B), dbuf

    const int t    = threadIdx.x;
    const int lane = t & 63;
    const int w    = t >> 6;              // wave 0..3  -> rem = rem0 + w
    const int bx   = blockIdx.x;
    const int b    = bx / 200;
    const int rem0 = (bx - b * 200) * 4;  // [0, 796]
    const int chunk  = blockIdx.y;        // 0: c2 in [0,16), 1: c2 in [16,32)
    const int c2base = chunk * 16;

    const float cw = colw[0];
    const float pw = posw[0];
    const float* __restrict__ in_b  = input + b * (CC * LL);
    float* __restrict__       out_b = out   + b * (CC * LL);

    // ---- stage cd for this block's 256 l2 values, coalesced ----
    {
        const int cd_base = b * (LL * KK2);
        #pragma unroll
        for (int j = 0; j < 25; ++j) {
            int flat = t + 256 * j;              // [0, 6400)
            int ci   = flat / 100;               // ii 0..63
            int pos  = flat - ci * 100;          // (rem-rem0)*25 + k2
            int gidx = cd_base + (rem0 + 800 * ci) * KK2 + pos;
            gidx = min(gidx, CDTOT - 1);         // clamp OOB tail (values unused)
            cds[ci * 101 + pos] = cd[gidx];
        }
    }
    __syncthreads();

    // ---- per-thread setup (mapping A) ----
    const int remU = __builtin_amdgcn_readfirstlane(rem0 + w);  // wave-uniform scalar
    const int ii   = lane;                                      // lane 63 / (62 & rem>=576) invalid; never stored

    int   A[KK2];
    float Wt[KK2];
    const float POS[KK2] = {8,5,4,5,8, 5,2,1,2,5, 4,1,0,1,4, 5,2,1,2,5, 8,5,4,5,8};

    #pragma unroll
    for (int k2 = 0; k2 < KK2; ++k2) {
        int t1 = 576 * k2 + remU;       // scalar from here...
        int q0 = t1 / 800;
        int r  = t1 - q0 * 800;
        int c  = r / 25;
        int s  = r - c * 25;
        int dy = s / 5 - 2;
        int dx = s % 5 - 2;             // ...to here
        int u  = 62 * k2 + q0 + ii;     // vector: +lane
        int ys = u / 224;               // [0,7]
        int xs = u - ys * 224;
        int xm = xs + dx;
        bool xok = (unsigned)xm < 224u;
        int xc = min(max(xm, 0), 223);
        float wgt = fmaf(cds[ii * 101 + w * 25 + k2], cw, POS[k2] * pw);
        Wt[k2] = xok ? wgt : 0.0f;      // x-mask folded into weight
        A[k2]  = c * LL + (ys + dy) * 224 + xc + c2base * 1568;
    }

    // ---- main loop over this chunk's 16 channels ----
    #pragma unroll 1
    for (int jj = 0; jj < 16; ++jj) {
        // issue the B-phase input load early (independent of gathers)
        const int remB = t & 3;
        const int iiB  = t >> 2;
        const int l2B  = rem0 + remB + 800 * iiB;
        const int idx  = (c2base + jj) * LL + min(l2B, LL - 1);
        const float iv = in_b[idx];

        float acc = 0.0f;
        const bool sp0  = (chunk == 0) && (jj == 0);    // c2 == 0
        const bool sp31 = (chunk == 1) && (jj == 15);   // c2 == 31
        if (sp0 | sp31) {
            #pragma unroll
            for (int k2 = 0; k2 < KK2; ++k2) {
                int t1 = 576 * k2 + remU;
                int q0 = t1 / 800;
                int r  = t1 - q0 * 800;
                int c  = r / 25;
                int s  = r - c * 25;
                int dy = s / 5 - 2;
                int dx = s % 5 - 2;
                int u  = 62 * k2 + q0 + ii;
                int ys = u / 224;
                int xs = u - ys * 224;
                int xc = min(max(xs + dx, 0), 223);
                int yy = ys + dy;                     // [-2, 9]
                int yb = sp0 ? max(yy, 0) : (217 + min(yy, 6));
                bool ok = sp0 ? (yy >= 0) : (yy <= 6);
                float v = in_b[c * LL + yb * 224 + xc];
                acc = fmaf(ok ? v : 0.0f, Wt[k2], acc);
            }
        } else {
            const int ofs = jj * 1568;
            #pragma unroll
            for (int k2 = 0; k2 < KK2; ++k2)
                acc = fmaf(in_b[A[k2] + ofs], Wt[k2], acc);
        }

        // exchange S to mapping B (contiguous-l2) for coalesced multiply+store
        float* sbuf = sx[jj & 1];
        sbuf[w * 65 + lane] = acc;
        __syncthreads();
        const float S = sbuf[remB * 65 + iiB];
        if (l2B < LL) out_b[idx] = S * iv;
        // no trailing barrier: double-buffered sx, next write targets other buf
    }
}

extern "C" void kernel_launch(void* const* d_in, const int* in_sizes, int n_in,
                              void* d_out, int out_size, void* d_ws, size_t ws_size,
                              hipStream_t stream) {
    const float* input = (const float*)d_in[0];
    const float* cdist = (const float*)d_in[1];
    const float* cwp   = (const float*)d_in[2];
    const float* pwp   = (const float*)d_in[3];
    float* o = (float*)d_out;

    dim3 grid(800, 2);   // 800 (b,rem0) tiles x 2 c2-chunks = 1600 blocks
    dim3 block(256);
    hipLaunchKernelGGL(conv_local_kernel, grid, block, 0, stream,
                       input, cdist, cwp, pwp, o);
}

// Round 3
// 164.155 us; speedup vs baseline: 1.9589x; 1.1057x over previous
//
#include <hip/hip_runtime.h>

// Problem constants
#define BB 4
#define CC 32
#define LL 50176              // 224*224
#define KK2 25
#define CDTOT (BB * LL * KK2) // 5,017,600 floats in cd

// out[b,c2,l2] = in[b,c2,l2] * sum_k2 Wt(b,l2,k2) * V(b,n),
//   n = c2*1254400 + k2*50176 + l2 ; decode l=n/800, c=(n%800)/25, s=n%25.
// Lanes stride l2 by 800 (l2 = rem + 800*ii):
//   (c,s,dy,dx) wave-uniform (scalar), gather addresses consecutive per lane.
// y-OOB only at c2==0 / c2==31 -> masked special iterations.
// jj batched by 4 (acc[4]) -> 6 barriers total, ~100 gathers in flight.
// LDS: cd staging buffer reused as exchange buffer after setup.
// XCD swizzle: batch b pinned to XCD pair {2b,2b+1} for L2 locality.

__global__ __launch_bounds__(256) void conv_local_kernel(
    const float* __restrict__ input,
    const float* __restrict__ cd,
    const float* __restrict__ colw,
    const float* __restrict__ posw,
    float* __restrict__ out)
{
    __shared__ float smem[64 * 101 + 8];  // setup: cds[64][101]; main: sx dbuf 2*1040 floats

    const int t    = threadIdx.x;
    const int lane = t & 63;
    const int w    = t >> 6;              // wave 0..3 -> rem = rem0 + w

    // XCD-locality swizzle (blocks assigned round-robin to 8 XCDs by blockIdx)
    const int bx   = blockIdx.x;          // 0..1599
    const int xcd  = bx & 7;
    const int slot = bx >> 3;             // 0..199
    const int b    = xcd >> 1;            // batch pinned to XCD pair
    const int j    = slot * 2 + (xcd & 1);// 0..399 within batch
    const int chunk  = j & 1;             // c2-chunk: [0,16) or [16,32)
    const int rem0   = (j >> 1) * 4;      // 0..796
    const int c2base = chunk * 16;

    const float cw = colw[0];
    const float pw = posw[0];
    const float* __restrict__ in_b  = input + b * (CC * LL);
    float* __restrict__       out_b = out   + b * (CC * LL);

    // ---- stage cd for this block's 256 l2 values, coalesced + nontemporal ----
    {
        const int cd_base = b * (LL * KK2);
        #pragma unroll
        for (int jld = 0; jld < 25; ++jld) {
            int flat = t + 256 * jld;            // [0, 6400)
            int ci   = flat / 100;               // ii 0..63
            int pos  = flat - ci * 100;          // (rem-rem0)*25 + k2
            int gidx = cd_base + (rem0 + 800 * ci) * KK2 + pos;
            gidx = min(gidx, CDTOT - 1);         // clamp OOB tail (values unused)
            smem[ci * 101 + pos] = __builtin_nontemporal_load(&cd[gidx]);
        }
    }
    __syncthreads();

    // ---- per-thread setup (mapping A) ----
    const int remU = __builtin_amdgcn_readfirstlane(rem0 + w);  // wave-uniform
    const int ii   = lane;

    int   A[KK2];
    float Wt[KK2];
    const float POS[KK2] = {8,5,4,5,8, 5,2,1,2,5, 4,1,0,1,4, 5,2,1,2,5, 8,5,4,5,8};

    #pragma unroll
    for (int k2 = 0; k2 < KK2; ++k2) {
        int t1 = 576 * k2 + remU;       // scalar...
        int q0 = t1 / 800;
        int r  = t1 - q0 * 800;
        int c  = r / 25;
        int s  = r - c * 25;
        int dy = s / 5 - 2;
        int dx = s % 5 - 2;
        int u  = 62 * k2 + q0 + ii;     // vector: +lane
        int ys = u / 224;               // [0,7]
        int xs = u - ys * 224;
        int xm = xs + dx;
        bool xok = (unsigned)xm < 224u;
        int xc = min(max(xm, 0), 223);
        float wgt = fmaf(smem[ii * 101 + w * 25 + k2], cw, POS[k2] * pw);
        Wt[k2] = xok ? wgt : 0.0f;      // x-mask folded into weight
        A[k2]  = c * LL + (ys + dy) * 224 + xc + c2base * 1568;
    }
    __syncthreads();   // smem reused as exchange buffer from here

    // mapping B (contiguous-l2) constants for coalesced multiply+store
    const int remB = t & 3;
    const int iiB  = t >> 2;
    const int l2B  = rem0 + remB + 800 * iiB;
    const bool okB = l2B < LL;
    const int idxB = min(l2B, LL - 1);

    // ---- main loop: 4 groups of 4 channels ----
    #pragma unroll 1
    for (int gg = 0; gg < 4; ++gg) {
        float acc[4];
        float iv[4];
        int   oidx[4];
        #pragma unroll
        for (int g = 0; g < 4; ++g) {
            oidx[g] = (c2base + gg * 4 + g) * LL + idxB;
            iv[g]   = in_b[oidx[g]];     // independent of gathers; overlaps
        }
        #pragma unroll
        for (int g = 0; g < 4; ++g) {
            const int jj = gg * 4 + g;
            const bool sp0  = (chunk == 0) && (jj == 0);    // c2 == 0
            const bool sp31 = (chunk == 1) && (jj == 15);   // c2 == 31
            float a = 0.0f;
            if (sp0 | sp31) {
                #pragma unroll
                for (int k2 = 0; k2 < KK2; ++k2) {
                    int t1 = 576 * k2 + remU;
                    int q0 = t1 / 800;
                    int r  = t1 - q0 * 800;
                    int c  = r / 25;
                    int s  = r - c * 25;
                    int dy = s / 5 - 2;
                    int dx = s % 5 - 2;
                    int u  = 62 * k2 + q0 + ii;
                    int ys = u / 224;
                    int xs = u - ys * 224;
                    int xc = min(max(xs + dx, 0), 223);
                    int yy = ys + dy;                     // [-2, 9]
                    int yb = sp0 ? max(yy, 0) : (217 + min(yy, 6));
                    bool ok = sp0 ? (yy >= 0) : (yy <= 6);
                    float v = in_b[c * LL + yb * 224 + xc];
                    a = fmaf(ok ? v : 0.0f, Wt[k2], a);
                }
            } else {
                const int ofs = jj * 1568;
                #pragma unroll
                for (int k2 = 0; k2 < KK2; ++k2)
                    a = fmaf(in_b[A[k2] + ofs], Wt[k2], a);
            }
            acc[g] = a;
        }

        // exchange S to mapping B; double-buffered (1040 floats each)
        float* sbuf = smem + (gg & 1) * 1040;
        #pragma unroll
        for (int g = 0; g < 4; ++g)
            sbuf[g * 260 + w * 65 + lane] = acc[g];
        __syncthreads();
        #pragma unroll
        for (int g = 0; g < 4; ++g) {
            float S = sbuf[g * 260 + remB * 65 + iiB];
            if (okB) __builtin_nontemporal_store(S * iv[g], &out_b[oidx[g]]);
        }
        // no trailing barrier: next group writes the other buffer; writes to
        // this buffer (gg+2) sit behind barrier(gg+1) which follows these reads
    }
}

extern "C" void kernel_launch(void* const* d_in, const int* in_sizes, int n_in,
                              void* d_out, int out_size, void* d_ws, size_t ws_size,
                              hipStream_t stream) {
    const float* input = (const float*)d_in[0];
    const float* cdist = (const float*)d_in[1];
    const float* cwp   = (const float*)d_in[2];
    const float* pwp   = (const float*)d_in[3];
    float* o = (float*)d_out;

    dim3 grid(1600);   // 4 b x 2 chunks x 200 rem0-tiles, XCD-swizzled in-kernel
    dim3 block(256);
    hipLaunchKernelGGL(conv_local_kernel, grid, block, 0, stream,
                       input, cdist, cwp, pwp, o);
}